// Round 14
// baseline (48.528 us; speedup 1.0000x reference)
//
#include <hip/hip_runtime.h>

#define LEAK 0.01f

typedef float v2f __attribute__((ext_vector_type(2)));
typedef _Float16 h2 __attribute__((ext_vector_type(2)));

// Problem constants
constexpr int H = 1024, W = 1024, NIMG = 4;
constexpr int GC = 12, GD = 12, GH = 16, GW = 16;
constexpr int NZ = GD - 1;           // 11 z0 values (z-pairs)
constexpr int CELLE = NZ * GC;       // 132 half2 per (y,x) grid cell
constexpr int CF4 = 33;              // float4 chunks per cell (132 h2 = 528 B)

// Tiling: 256 threads (128x2), each thread does 2 pixels along x -> 256x2 tile
constexpr int PX = 2;
constexpr int BX = 128, BY = 2;
constexpr int TILE_W = BX * PX;      // 256
constexpr int XS = 6;                // x-cell footprint of a 256-wide tile
constexpr int SGN = BY * XS * CF4;   // 396 float4 of sgrid staging

// Lane-major fp32 image slab: pixel x <-> (j=(x-wb)&1, lanepos=(x-wb)>>1)
// word = lanepos + 2 (covers lanepos -2..129); JW=132 exact.
constexpr int IMROWS = BY + 2;       // 4 rows: hb-1 .. hb+2
constexpr int NCHUNK = 66;           // float4 chunks per (ch,row): gx = wb-4 .. wb+259
constexpr int JW     = 132;          // words per j-plane
// simg size: 3ch * 4rows * 2j * 132 * 4B = 12672 B; sgrid: 2*6*132*4B = 6336 B

static __device__ __forceinline__ h2 bch2(float f) {
    return __builtin_bit_cast(h2, f);
}
static __device__ __forceinline__ float bcf(h2 v) {
    return __builtin_bit_cast(float, v);
}
// cvt_pkrtz returns __fp16x2; bit-cast to our h2 (_Float16x2) — same bits.
static __device__ __forceinline__ h2 pkrtz(float a, float b) {
    return __builtin_bit_cast(h2, __builtin_amdgcn_cvt_pkrtz(a, b));
}

static __device__ __forceinline__ float fdot2f(h2 a, h2 b, float c) {
#if __has_builtin(__builtin_amdgcn_fdot2)
    return __builtin_amdgcn_fdot2(a, b, c, false);
#else
    return (float)a.x * (float)b.x + (float)a.y * (float)b.y + c;
#endif
}

// ---- pre-kernel: build z-pair half2 table in ws ----
// table layout: [n][y*16+x][z0*12+c]  (132 half2 = 528 B contiguous per cell)
__global__ __launch_bounds__(256) void pairgen(const float* __restrict__ grid,
                                               h2* __restrict__ table) {
    const int n  = blockIdx.x / NZ;
    const int z0 = blockIdx.x % NZ;
    const int yx = threadIdx.x;      // 0..255, coalesced over lanes
    const float* src = grid + (size_t)n * GC * GD * GH * GW + yx;
    h2* dst = table + ((size_t)n * 256 + yx) * CELLE + z0 * GC;
    #pragma unroll
    for (int c = 0; c < GC; ++c) {
        float a = src[(c * GD + z0) * 256];
        float b = src[(c * GD + z0 + 1) * 256];
        dst[c] = pkrtz(a, b);
    }
}

__global__ __launch_bounds__(256, 8) void hdrnet_fused(
    const float* __restrict__ grid,   // (N,12,12,16,16)
    const float* __restrict__ full,   // (N,3,H,W)
    const float* __restrict__ w1,     // (3,3,1,1)
    const float* __restrict__ w3,     // (3,3,3,3)
    const float* __restrict__ b3,     // (3)
    const float* __restrict__ bias,   // (1)
    const h2* __restrict__ table,     // pair table or nullptr
    float* __restrict__ out)          // (N,3,H,W)
{
    __shared__ __align__(16) float simg[3 * IMROWS * 2 * JW];   // 12672 B
    __shared__ __align__(16) h2 sgrid[BY * XS * CELLE];         // 6336 B

    const int n  = blockIdx.z;
    const int wb = blockIdx.x * TILE_W;
    const int hb = blockIdx.y * BY;

    const float scale = 15.0f / 1023.0f;
    const int xlo = (int)(wb * scale);

    const int tid = threadIdx.y * BX + threadIdx.x;
    const size_t plane = (size_t)H * W;
    const float* fn = full + (size_t)n * 3 * plane;

    // ---- issue table loads FIRST (latency hidden under image staging) ----
    float4 tA[2], tB[2];
    const bool ttail = (tid < SGN - 256);   // 140 threads do a 2nd element
    if (table) {
        const float4* tsrc = (const float4*)(table + (size_t)n * 256 * CELLE);
        {
            int e  = tid;
            int r  = e / (XS * CF4);
            int t2 = e - r * (XS * CF4);
            int lx = t2 / CF4, q = t2 - lx * CF4;
            int y0 = min((int)((float)(hb + r) * scale), GH - 2);
            int xi = min(xlo + lx, GW - 1);
            tA[0] = tsrc[(y0 * GW + xi) * CF4 + q];
            tB[0] = tsrc[((y0 + 1) * GW + xi) * CF4 + q];
        }
        if (ttail) {
            int e  = 256 + tid;
            int r  = e / (XS * CF4);
            int t2 = e - r * (XS * CF4);
            int lx = t2 / CF4, q = t2 - lx * CF4;
            int y0 = min((int)((float)(hb + r) * scale), GH - 2);
            int xi = min(xlo + lx, GW - 1);
            tA[1] = tsrc[(y0 * GW + xi) * CF4 + q];
            tB[1] = tsrc[((y0 + 1) * GW + xi) * CF4 + q];
        }
    }

    // ---- stage fullres tile into LDS, lane-major fp32 j-planes ----
    for (int e = tid; e < 3 * IMROWS * NCHUNK; e += BX * BY) {   // 792 chunks
        int ch = e / (IMROWS * NCHUNK);
        int t  = e - ch * (IMROWS * NCHUNK);
        int r  = t / NCHUNK, m = t - r * NCHUNK;
        int yy = hb + r - 1;
        int gx = wb - 4 + 4 * m;
        float4 v = (float4){0.0f, 0.0f, 0.0f, 0.0f};
        if ((unsigned)yy < (unsigned)H && (unsigned)gx < (unsigned)W)
            v = *(const float4*)(fn + (size_t)ch * plane + (size_t)yy * W + gx);
        // gx-wb = 4m-4: j0 words 2m,2m+1 get v.x,v.z; j1 words 2m,2m+1 get v.y,v.w
        float* j0 = &simg[((ch * IMROWS + r) * 2 + 0) * JW];
        float* j1 = j0 + JW;
        j0[2 * m]     = v.x;
        j0[2 * m + 1] = v.z;
        j1[2 * m]     = v.y;
        j1[2 * m + 1] = v.w;
    }
    __syncthreads();   // image slab ready

    // ---- sgrid: y-lerp from registers, write LDS (conv below overlaps) ----
    if (table) {
        float4* sdst = (float4*)sgrid;
        #pragma unroll
        for (int it = 0; it < 2; ++it) {
            if (it == 1 && !ttail) break;
            int e = (it == 1) ? (256 + tid) : tid;
            int r = e / (XS * CF4);
            float fy = (float)(hb + r) * scale;
            float ty = fy - (float)min((int)fy, GH - 2);
            _Float16 t1 = (_Float16)ty, t0 = (_Float16)(1.0f - ty);
            h2 w0v = (h2){t0, t0}, w1v = (h2){t1, t1};
            float4 A = tA[it], B = tB[it], R;
            R.x = bcf(bch2(A.x) * w0v + bch2(B.x) * w1v);
            R.y = bcf(bch2(A.y) * w0v + bch2(B.y) * w1v);
            R.z = bcf(bch2(A.z) * w0v + bch2(B.z) * w1v);
            R.w = bcf(bch2(A.w) * w0v + bch2(B.w) * w1v);
            sdst[e] = R;
        }
    } else {
        const float* gnn = grid + (size_t)n * GC * GD * GH * GW;
        for (int e = tid; e < BY * XS * CELLE; e += BX * BY) {
            int r  = e / (XS * CELLE);
            int t  = e - r * (XS * CELLE);
            int lx = t / CELLE, u = t - lx * CELLE;
            int z0 = u / GC, c = u - z0 * GC;
            float fy = (float)(hb + r) * scale;
            int y0 = min((int)fy, GH - 2);
            float ty = fy - (float)y0;
            int xi = min(xlo + lx, GW - 1);
            const float* gp = gnn + ((c * GD + z0) * GH + y0) * GW + xi;
            float a0 = gp[0],  a1 = gp[256];
            float b0 = gp[16], b1 = gp[272];
            sgrid[e] = pkrtz(fmaf(b0 - a0, ty, a0), fmaf(b1 - a1, ty, a1));
        }
    }

    const int h  = hb + threadIdx.y;
    const int L  = threadIdx.x;            // 0..127
    const int w0 = wb + 2 * L;

    // ---- weights to registers ----
    float w1c[3][3];
    #pragma unroll
    for (int o = 0; o < 3; ++o)
        #pragma unroll
        for (int i = 0; i < 3; ++i)
            w1c[o][i] = w1[o * 3 + i];
    const float biasv = bias[0];

    // ---- 3x3 conv over 3 ch for 2 pixels; conflict-free lane-major reads ----
    v2f a3p[3];
    #pragma unroll
    for (int o = 0; o < 3; ++o) {
        float b = b3[o];
        a3p[o] = (v2f){b, b};
    }
    v2f rgbp[3];   // center pair (w0, w0+1) per channel

    #pragma unroll
    for (int i = 0; i < 3; ++i) {
        #pragma unroll
        for (int dy = 0; dy < 3; ++dy) {
            const float* j0 = &simg[((i * IMROWS + threadIdx.y + dy) * 2) * JW];
            const float* j1 = j0 + JW;
            float row[4];                  // pixels w0-1 .. w0+2
            row[0] = j1[L + 1];
            row[1] = j0[L + 2];
            row[2] = j1[L + 2];
            row[3] = j0[L + 3];
            if (dy == 1) {
                #pragma unroll
                for (int i2 = 0; i2 < 1; ++i2) {}
                rgbp[i] = (v2f){row[1], row[2]};
            }
            #pragma unroll
            for (int o = 0; o < 3; ++o) {
                const float* kp = w3 + ((o * 3 + i) * 3 + dy) * 3;
                #pragma unroll
                for (int t = 0; t < 3; ++t) {
                    const float kt = kp[t];
                    v2f kv = (v2f){kt, kt};
                    a3p[o] = __builtin_elementwise_fma(
                        kv, (v2f){row[t], row[t + 1]}, a3p[o]);
                }
            }
        }
    }
    __syncthreads();   // sgrid ready

    const int srow = threadIdx.y * XS;     // this thread-row's cell base
    const float4* sg4 = (const float4*)sgrid;

    float ovv[3][PX];

    #pragma unroll
    for (int j = 0; j < PX; ++j) {
        // guide
        float gacc = 0.0f;
        #pragma unroll
        for (int o = 0; o < 3; ++o) {
            float x1 = fmaf(w1c[o][0], rgbp[0][j],
                       fmaf(w1c[o][1], rgbp[1][j], w1c[o][2] * rgbp[2][j]));
            x1 = (x1 > 0.0f) ? x1 : LEAK * x1;
            float x3 = a3p[o][j];
            x3 = (x3 > 0.0f) ? x3 : LEAK * x3;
            gacc += x1 + x3;
        }
        float g = fmaf(gacc, (1.0f / 3.0f), biasv);
        g = fminf(fmaxf(g, 0.0f), 1.0f);

        // slice coords (y already folded into LDS)
        float fx = (float)(w0 + j) * scale;
        int x0 = (int)fx;
        x0 = min(x0, GW - 2);
        float tx = fx - (float)x0;
        const int lxr = x0 - xlo;      // 0..5

        float fz = g * 11.0f;
        int z0 = (int)fz;
        z0 = min(z0, GD - 2);
        float tz = fz - (float)z0;
        h2 hz = pkrtz(1.0f - tz, tz);
        _Float16 hx0 = (_Float16)(1.0f - tx), hx1 = (_Float16)tx;
        h2 wA = hz * (h2){hx0, hx0};   // v_pk_mul_f16
        h2 wB = hz * (h2){hx1, hx1};

        const float4* pA = sg4 + (srow + lxr) * CF4 + z0 * 3;
        const float4* pB = pA + CF4;
        float4 A0 = pA[0], A1 = pA[1], A2 = pA[2];
        float4 B0 = pB[0], B1 = pB[1], B2 = pB[2];

        float co[12];
        co[0]  = fdot2f(wA, bch2(A0.x), fdot2f(wB, bch2(B0.x), 0.0f));
        co[1]  = fdot2f(wA, bch2(A0.y), fdot2f(wB, bch2(B0.y), 0.0f));
        co[2]  = fdot2f(wA, bch2(A0.z), fdot2f(wB, bch2(B0.z), 0.0f));
        co[3]  = fdot2f(wA, bch2(A0.w), fdot2f(wB, bch2(B0.w), 0.0f));
        co[4]  = fdot2f(wA, bch2(A1.x), fdot2f(wB, bch2(B1.x), 0.0f));
        co[5]  = fdot2f(wA, bch2(A1.y), fdot2f(wB, bch2(B1.y), 0.0f));
        co[6]  = fdot2f(wA, bch2(A1.z), fdot2f(wB, bch2(B1.z), 0.0f));
        co[7]  = fdot2f(wA, bch2(A1.w), fdot2f(wB, bch2(B1.w), 0.0f));
        co[8]  = fdot2f(wA, bch2(A2.x), fdot2f(wB, bch2(B2.x), 0.0f));
        co[9]  = fdot2f(wA, bch2(A2.y), fdot2f(wB, bch2(B2.y), 0.0f));
        co[10] = fdot2f(wA, bch2(A2.z), fdot2f(wB, bch2(B2.z), 0.0f));
        co[11] = fdot2f(wA, bch2(A2.w), fdot2f(wB, bch2(B2.w), 0.0f));

        // apply
        const float r = rgbp[0][j], gg = rgbp[1][j], b = rgbp[2][j];
        ovv[0][j] = fmaf(co[0], r, fmaf(co[1],  gg, fmaf(co[2],  b, co[3])));
        ovv[1][j] = fmaf(co[4], r, fmaf(co[5],  gg, fmaf(co[6],  b, co[7])));
        ovv[2][j] = fmaf(co[8], r, fmaf(co[9],  gg, fmaf(co[10], b, co[11])));
    }

    // ---- coalesced float2 stores, one per channel ----
    float* ob = out + (size_t)n * 3 * plane + (size_t)h * W + w0;
    *(float2*)(ob)             = (float2){ovv[0][0], ovv[0][1]};
    *(float2*)(ob + plane)     = (float2){ovv[1][0], ovv[1][1]};
    *(float2*)(ob + 2 * plane) = (float2){ovv[2][0], ovv[2][1]};
}

extern "C" void kernel_launch(void* const* d_in, const int* in_sizes, int n_in,
                              void* d_out, int out_size, void* d_ws, size_t ws_size,
                              hipStream_t stream) {
    const float* grid_p = (const float*)d_in[0];
    const float* full_p = (const float*)d_in[1];
    const float* w1_p   = (const float*)d_in[2];
    const float* w3_p   = (const float*)d_in[3];
    const float* b3_p   = (const float*)d_in[4];
    const float* bias_p = (const float*)d_in[5];
    float* out_p = (float*)d_out;

    const size_t tbytes = (size_t)NIMG * 256 * CELLE * sizeof(h2);  // 540,672 B
    h2* table = (d_ws && ws_size >= tbytes) ? (h2*)d_ws : nullptr;

    if (table) {
        hipLaunchKernelGGL(pairgen, dim3(NIMG * NZ), dim3(256), 0, stream,
                           grid_p, table);
    }

    dim3 block(BX, BY, 1);
    dim3 grid_dim(W / TILE_W, H / BY, NIMG);
    hipLaunchKernelGGL(hdrnet_fused, grid_dim, block, 0, stream,
                       grid_p, full_p, w1_p, w3_p, b3_p, bias_p, table, out_p);
}

// Round 15
// 39.964 us; speedup vs baseline: 1.2143x; 1.2143x over previous
//
#include <hip/hip_runtime.h>

#define LEAK 0.01f

typedef float v2f __attribute__((ext_vector_type(2)));
typedef _Float16 h2 __attribute__((ext_vector_type(2)));

// Problem constants
constexpr int H = 1024, W = 1024, NIMG = 4;
constexpr int GC = 12, GD = 12, GH = 16, GW = 16;
constexpr int NZ = GD - 1;           // 11 z0 values (z-pairs)
constexpr int CELLE = NZ * GC;       // 132 half2 per (y,x) grid cell
constexpr int CF4 = 33;              // float4 chunks per cell (132 h2 = 528 B)

// Tiling: 256 threads (64x4), each thread does 4 pixels along x -> 256x4 tile
constexpr int PX = 4;
constexpr int BX = 64, BY = 4;
constexpr int TILE_W = BX * PX;      // 256
constexpr int XS = 6;                // x-cell footprint of a 256-wide tile
constexpr int SGN = BY * XS * CF4;   // 792 float4 of sgrid staging

// Lane-major fp32 image slab: pixel x <-> (j=(x-wb)&3, lanepos=(x-wb)>>2)
// layout simg[ch][row][j][IMJW], word = lanepos+1 (covers lanepos -1..64)
constexpr int IMROWS = BY + 2;       // 6 rows: hb-1 .. hb+4
constexpr int NCHUNK = 66;           // float4 chunks per (ch,row): gx = wb-4 .. wb+259
constexpr int IMJW   = 68;           // padded j-plane width (66 used)
constexpr int CHUNKS = 3 * IMROWS * NCHUNK;            // 1188
constexpr int NIT    = (CHUNKS + BX * BY - 1) / (BX * BY);  // 5

static __device__ __forceinline__ h2 bch2(float f) {
    return __builtin_bit_cast(h2, f);
}
static __device__ __forceinline__ float bcf(h2 v) {
    return __builtin_bit_cast(float, v);
}
// cvt_pkrtz returns __fp16x2; bit-cast to our h2 (_Float16x2) — same bits.
static __device__ __forceinline__ h2 pkrtz(float a, float b) {
    return __builtin_bit_cast(h2, __builtin_amdgcn_cvt_pkrtz(a, b));
}

static __device__ __forceinline__ float fdot2f(h2 a, h2 b, float c) {
#if __has_builtin(__builtin_amdgcn_fdot2)
    return __builtin_amdgcn_fdot2(a, b, c, false);
#else
    return (float)a.x * (float)b.x + (float)a.y * (float)b.y + c;
#endif
}

// ---- pre-kernel: build z-pair half2 table in ws ----
// table layout: [n][y*16+x][z0*12+c]  (132 half2 = 528 B contiguous per cell)
__global__ __launch_bounds__(256) void pairgen(const float* __restrict__ grid,
                                               h2* __restrict__ table) {
    const int n  = blockIdx.x / NZ;
    const int z0 = blockIdx.x % NZ;
    const int yx = threadIdx.x;      // 0..255, coalesced over lanes
    const float* src = grid + (size_t)n * GC * GD * GH * GW + yx;
    h2* dst = table + ((size_t)n * 256 + yx) * CELLE + z0 * GC;
    #pragma unroll
    for (int c = 0; c < GC; ++c) {
        float a = src[(c * GD + z0) * 256];
        float b = src[(c * GD + z0 + 1) * 256];
        dst[c] = pkrtz(a, b);
    }
}

__global__ __launch_bounds__(256) void hdrnet_fused(
    const float* __restrict__ grid,   // (N,12,12,16,16)
    const float* __restrict__ full,   // (N,3,H,W)
    const float* __restrict__ w1,     // (3,3,1,1)
    const float* __restrict__ w3,     // (3,3,3,3)
    const float* __restrict__ b3,     // (3)
    const float* __restrict__ bias,   // (1)
    const h2* __restrict__ table,     // pair table or nullptr
    float* __restrict__ out)          // (N,3,H,W)
{
    __shared__ __align__(16) float simg[3 * IMROWS * 4 * IMJW]; // 19584 B
    __shared__ __align__(16) h2 sgrid[BY * XS * CELLE];         // 12672 B

    const int n  = blockIdx.z;
    const int wb = blockIdx.x * TILE_W;
    const int hb = blockIdx.y * BY;

    const float scale = 15.0f / 1023.0f;
    const int xlo = (int)(wb * scale);

    const int tid = threadIdx.y * BX + threadIdx.x;
    const size_t plane = (size_t)H * W;
    const float* fn = full + (size_t)n * 3 * plane;

    // ---- issue table loads FIRST (oldest in vmcnt queue) ----
    float4 tA[4], tB[4];
    const bool ttail = (tid < SGN - 768);   // 24 threads do a 4th element
    if (table) {
        const float4* tsrc = (const float4*)(table + (size_t)n * 256 * CELLE);
        #pragma unroll
        for (int it = 0; it < 3; ++it) {
            int e  = tid + 256 * it;
            int r  = e / (XS * CF4);
            int t2 = e - r * (XS * CF4);
            int lx = t2 / CF4, q = t2 - lx * CF4;
            int y0 = min((int)((float)(hb + r) * scale), GH - 2);
            int xi = min(xlo + lx, GW - 1);
            tA[it] = tsrc[(y0 * GW + xi) * CF4 + q];
            tB[it] = tsrc[((y0 + 1) * GW + xi) * CF4 + q];
        }
        if (ttail) {
            int e  = 768 + tid;
            int r  = e / (XS * CF4);
            int t2 = e - r * (XS * CF4);
            int lx = t2 / CF4, q = t2 - lx * CF4;
            int y0 = min((int)((float)(hb + r) * scale), GH - 2);
            int xi = min(xlo + lx, GW - 1);
            tA[3] = tsrc[(y0 * GW + xi) * CF4 + q];
            tB[3] = tsrc[((y0 + 1) * GW + xi) * CF4 + q];
        }
    }

    // ---- stage fullres tile: batch ALL loads into regs, THEN write LDS ----
    float4 vv[NIT];
    int    loff[NIT];
    #pragma unroll
    for (int it = 0; it < NIT; ++it) {
        int e = tid + 256 * it;
        loff[it] = -1;
        if (e < CHUNKS) {
            int ch = e / (IMROWS * NCHUNK);
            int t  = e - ch * (IMROWS * NCHUNK);
            int r  = t / NCHUNK, m = t - r * NCHUNK;
            int yy = hb + r - 1;
            int gx = wb - 4 + 4 * m;
            float4 v = (float4){0.0f, 0.0f, 0.0f, 0.0f};
            if ((unsigned)yy < (unsigned)H && (unsigned)gx < (unsigned)W)
                v = *(const float4*)(fn + (size_t)ch * plane + (size_t)yy * W + gx);
            vv[it]   = v;
            loff[it] = ((ch * IMROWS + r) * 4) * IMJW + m;
        }
    }
    #pragma unroll
    for (int it = 0; it < NIT; ++it) {
        if (loff[it] >= 0) {
            float* wp = &simg[loff[it]];
            wp[0 * IMJW] = vv[it].x;
            wp[1 * IMJW] = vv[it].y;
            wp[2 * IMJW] = vv[it].z;
            wp[3 * IMJW] = vv[it].w;
        }
    }
    __syncthreads();   // image slab ready

    // ---- sgrid: y-lerp from registers, write LDS (conv below overlaps) ----
    if (table) {
        float4* sdst = (float4*)sgrid;
        #pragma unroll
        for (int it = 0; it < 4; ++it) {
            if (it == 3 && !ttail) break;
            int e = (it == 3) ? (768 + tid) : (tid + 256 * it);
            int r = e / (XS * CF4);
            float fy = (float)(hb + r) * scale;
            float ty = fy - (float)min((int)fy, GH - 2);
            _Float16 t1 = (_Float16)ty, t0 = (_Float16)(1.0f - ty);
            h2 w0v = (h2){t0, t0}, w1v = (h2){t1, t1};
            float4 A = tA[it], B = tB[it], R;
            R.x = bcf(bch2(A.x) * w0v + bch2(B.x) * w1v);
            R.y = bcf(bch2(A.y) * w0v + bch2(B.y) * w1v);
            R.z = bcf(bch2(A.z) * w0v + bch2(B.z) * w1v);
            R.w = bcf(bch2(A.w) * w0v + bch2(B.w) * w1v);
            sdst[e] = R;
        }
    } else {
        const float* gnn = grid + (size_t)n * GC * GD * GH * GW;
        for (int e = tid; e < BY * XS * CELLE; e += BX * BY) {
            int r  = e / (XS * CELLE);
            int t  = e - r * (XS * CELLE);
            int lx = t / CELLE, u = t - lx * CELLE;
            int z0 = u / GC, c = u - z0 * GC;
            float fy = (float)(hb + r) * scale;
            int y0 = min((int)fy, GH - 2);
            float ty = fy - (float)y0;
            int xi = min(xlo + lx, GW - 1);
            const float* gp = gnn + ((c * GD + z0) * GH + y0) * GW + xi;
            float a0 = gp[0],  a1 = gp[256];
            float b0 = gp[16], b1 = gp[272];
            sgrid[e] = pkrtz(fmaf(b0 - a0, ty, a0), fmaf(b1 - a1, ty, a1));
        }
    }

    const int h  = hb + threadIdx.y;
    const int w0 = wb + threadIdx.x * PX;

    // ---- weights to registers ----
    float w1c[3][3];
    #pragma unroll
    for (int o = 0; o < 3; ++o)
        #pragma unroll
        for (int i = 0; i < 3; ++i)
            w1c[o][i] = w1[o * 3 + i];
    const float biasv = bias[0];

    // ---- 3x3 conv over 3 ch for 4 pixels; rows via conflict-free lane-major
    //      LDS reads, zero unpack (runs between barriers) ----
    v2f a3p[3][2];
    #pragma unroll
    for (int o = 0; o < 3; ++o) {
        float b = b3[o];
        a3p[o][0] = (v2f){b, b};
        a3p[o][1] = (v2f){b, b};
    }
    float rgb[3][PX];
    const int L = threadIdx.x;

    #pragma unroll
    for (int i = 0; i < 3; ++i) {
        #pragma unroll
        for (int dy = 0; dy < 3; ++dy) {
            const float* jp = &simg[((i * IMROWS + threadIdx.y + dy) * 4) * IMJW];
            float row[8];   // row[k] = pixel x = w0-1+k
            row[0] = jp[3 * IMJW + L];       // c=4L-1
            row[1] = jp[L + 1];              // c=4L
            row[2] = jp[1 * IMJW + L + 1];
            row[3] = jp[2 * IMJW + L + 1];
            row[4] = jp[3 * IMJW + L + 1];
            row[5] = jp[L + 2];              // c=4L+4
            row[6] = jp[1 * IMJW + L + 2];
            row[7] = jp[2 * IMJW + L + 2];
            if (dy == 1) {
                #pragma unroll
                for (int j = 0; j < PX; ++j) rgb[i][j] = row[1 + j];
            }
            #pragma unroll
            for (int o = 0; o < 3; ++o) {
                const float* kp = w3 + ((o * 3 + i) * 3 + dy) * 3;
                #pragma unroll
                for (int t = 0; t < 3; ++t) {
                    const float kt = kp[t];
                    v2f kv = (v2f){kt, kt};
                    a3p[o][0] = __builtin_elementwise_fma(
                        kv, (v2f){row[t], row[t + 1]}, a3p[o][0]);
                    a3p[o][1] = __builtin_elementwise_fma(
                        kv, (v2f){row[t + 2], row[t + 3]}, a3p[o][1]);
                }
            }
        }
    }
    __syncthreads();   // sgrid ready

    const int srow = threadIdx.y * XS;       // this thread-row's cell base
    const float4* sg4 = (const float4*)sgrid;

    float4 ov0, ov1, ov2;
    float* ov0p = &ov0.x; float* ov1p = &ov1.x; float* ov2p = &ov2.x;

    #pragma unroll
    for (int j = 0; j < PX; ++j) {
        // guide
        float gacc = 0.0f;
        #pragma unroll
        for (int o = 0; o < 3; ++o) {
            float x1 = fmaf(w1c[o][0], rgb[0][j],
                       fmaf(w1c[o][1], rgb[1][j], w1c[o][2] * rgb[2][j]));
            x1 = (x1 > 0.0f) ? x1 : LEAK * x1;
            float x3 = a3p[o][j >> 1][j & 1];
            x3 = (x3 > 0.0f) ? x3 : LEAK * x3;
            gacc += x1 + x3;
        }
        float g = fmaf(gacc, (1.0f / 3.0f), biasv);
        g = fminf(fmaxf(g, 0.0f), 1.0f);

        // slice coords (y already folded into LDS)
        float fx = (float)(w0 + j) * scale;
        int x0 = (int)fx;
        x0 = min(x0, GW - 2);
        float tx = fx - (float)x0;
        const int lxr = x0 - xlo;      // 0..4

        float fz = g * 11.0f;
        int z0 = (int)fz;
        z0 = min(z0, GD - 2);
        float tz = fz - (float)z0;
        h2 hz = pkrtz(1.0f - tz, tz);
        _Float16 hx0 = (_Float16)(1.0f - tx), hx1 = (_Float16)tx;
        h2 wA = hz * (h2){hx0, hx0};   // v_pk_mul_f16
        h2 wB = hz * (h2){hx1, hx1};

        const float4* pA = sg4 + (srow + lxr) * CF4 + z0 * 3;
        const float4* pB = pA + CF4;
        float4 A0 = pA[0], A1 = pA[1], A2 = pA[2];
        float4 B0 = pB[0], B1 = pB[1], B2 = pB[2];

        float co[12];
        co[0]  = fdot2f(wA, bch2(A0.x), fdot2f(wB, bch2(B0.x), 0.0f));
        co[1]  = fdot2f(wA, bch2(A0.y), fdot2f(wB, bch2(B0.y), 0.0f));
        co[2]  = fdot2f(wA, bch2(A0.z), fdot2f(wB, bch2(B0.z), 0.0f));
        co[3]  = fdot2f(wA, bch2(A0.w), fdot2f(wB, bch2(B0.w), 0.0f));
        co[4]  = fdot2f(wA, bch2(A1.x), fdot2f(wB, bch2(B1.x), 0.0f));
        co[5]  = fdot2f(wA, bch2(A1.y), fdot2f(wB, bch2(B1.y), 0.0f));
        co[6]  = fdot2f(wA, bch2(A1.z), fdot2f(wB, bch2(B1.z), 0.0f));
        co[7]  = fdot2f(wA, bch2(A1.w), fdot2f(wB, bch2(B1.w), 0.0f));
        co[8]  = fdot2f(wA, bch2(A2.x), fdot2f(wB, bch2(B2.x), 0.0f));
        co[9]  = fdot2f(wA, bch2(A2.y), fdot2f(wB, bch2(B2.y), 0.0f));
        co[10] = fdot2f(wA, bch2(A2.z), fdot2f(wB, bch2(B2.z), 0.0f));
        co[11] = fdot2f(wA, bch2(A2.w), fdot2f(wB, bch2(B2.w), 0.0f));

        // apply
        const float r = rgb[0][j], gg = rgb[1][j], b = rgb[2][j];
        ov0p[j] = fmaf(co[0], r, fmaf(co[1],  gg, fmaf(co[2],  b, co[3])));
        ov1p[j] = fmaf(co[4], r, fmaf(co[5],  gg, fmaf(co[6],  b, co[7])));
        ov2p[j] = fmaf(co[8], r, fmaf(co[9],  gg, fmaf(co[10], b, co[11])));
    }

    // ---- coalesced float4 stores ----
    float* ob = out + (size_t)n * 3 * plane + (size_t)h * W + w0;
    *(float4*)(ob)             = ov0;
    *(float4*)(ob + plane)     = ov1;
    *(float4*)(ob + 2 * plane) = ov2;
}

extern "C" void kernel_launch(void* const* d_in, const int* in_sizes, int n_in,
                              void* d_out, int out_size, void* d_ws, size_t ws_size,
                              hipStream_t stream) {
    const float* grid_p = (const float*)d_in[0];
    const float* full_p = (const float*)d_in[1];
    const float* w1_p   = (const float*)d_in[2];
    const float* w3_p   = (const float*)d_in[3];
    const float* b3_p   = (const float*)d_in[4];
    const float* bias_p = (const float*)d_in[5];
    float* out_p = (float*)d_out;

    const size_t tbytes = (size_t)NIMG * 256 * CELLE * sizeof(h2);  // 540,672 B
    h2* table = (d_ws && ws_size >= tbytes) ? (h2*)d_ws : nullptr;

    if (table) {
        hipLaunchKernelGGL(pairgen, dim3(NIMG * NZ), dim3(256), 0, stream,
                           grid_p, table);
    }

    dim3 block(BX, BY, 1);
    dim3 grid_dim(W / TILE_W, H / BY, NIMG);
    hipLaunchKernelGGL(hdrnet_fused, grid_dim, block, 0, stream,
                       grid_p, full_p, w1_p, w3_p, b3_p, bias_p, table, out_p);
}

// Round 16
// 39.813 us; speedup vs baseline: 1.2189x; 1.0038x over previous
//
#include <hip/hip_runtime.h>

#define LEAK 0.01f

typedef float v2f __attribute__((ext_vector_type(2)));
typedef _Float16 h2 __attribute__((ext_vector_type(2)));

// Problem constants
constexpr int H = 1024, W = 1024, NIMG = 4;
constexpr int GC = 12, GD = 12, GH = 16, GW = 16;
constexpr int NZ = GD - 1;           // 11 z0 values (z-pairs)
constexpr int CELLE = NZ * GC;       // 132 half2 per (y,x) grid cell
constexpr int CF4 = 33;              // float4 chunks per cell (132 h2 = 528 B)

// Tiling: 256 threads (64x4), each thread does 4 pixels along x -> 256x4 tile
constexpr int PX = 4;
constexpr int BX = 64, BY = 4;
constexpr int TILE_W = BX * PX;      // 256
constexpr int XS = 6;                // x-cell footprint of a 256-wide tile
constexpr int SGN = BY * XS * CF4;   // 792 float4 of sgrid staging

// Lane-major fp32 image slab: pixel x <-> (j=(x-wb)&3, lanepos=(x-wb)>>2)
// layout simg[ch][row][j][IMJW], word = lanepos+1 (covers lanepos -1..64)
constexpr int IMROWS = BY + 2;       // 6 rows: hb-1 .. hb+4
constexpr int NCHUNK = 66;           // float4 chunks per (ch,row): gx = wb-4 .. wb+259
constexpr int IMJW   = 68;           // padded j-plane width (66 used)
constexpr int CHUNKS = 3 * IMROWS * NCHUNK;            // 1188
constexpr int NIT    = (CHUNKS + BX * BY - 1) / (BX * BY);  // 5

static __device__ __forceinline__ h2 bch2(float f) {
    return __builtin_bit_cast(h2, f);
}
static __device__ __forceinline__ float bcf(h2 v) {
    return __builtin_bit_cast(float, v);
}
// cvt_pkrtz returns __fp16x2; bit-cast to our h2 (_Float16x2) — same bits.
static __device__ __forceinline__ h2 pkrtz(float a, float b) {
    return __builtin_bit_cast(h2, __builtin_amdgcn_cvt_pkrtz(a, b));
}

static __device__ __forceinline__ float fdot2f(h2 a, h2 b, float c) {
#if __has_builtin(__builtin_amdgcn_fdot2)
    return __builtin_amdgcn_fdot2(a, b, c, false);
#else
    return (float)a.x * (float)b.x + (float)a.y * (float)b.y + c;
#endif
}

// ---- pre-kernel: build z-pair half2 table in ws ----
// table layout: [n][y*16+x][z0*12+c]  (132 half2 = 528 B contiguous per cell)
__global__ __launch_bounds__(256) void pairgen(const float* __restrict__ grid,
                                               h2* __restrict__ table) {
    const int n  = blockIdx.x / NZ;
    const int z0 = blockIdx.x % NZ;
    const int yx = threadIdx.x;      // 0..255, coalesced over lanes
    const float* src = grid + (size_t)n * GC * GD * GH * GW + yx;
    h2* dst = table + ((size_t)n * 256 + yx) * CELLE + z0 * GC;
    #pragma unroll
    for (int c = 0; c < GC; ++c) {
        float a = src[(c * GD + z0) * 256];
        float b = src[(c * GD + z0 + 1) * 256];
        dst[c] = pkrtz(a, b);
    }
}

__global__ __launch_bounds__(256) void hdrnet_fused(
    const float* __restrict__ grid,   // (N,12,12,16,16)
    const float* __restrict__ full,   // (N,3,H,W)
    const float* __restrict__ w1,     // (3,3,1,1)
    const float* __restrict__ w3,     // (3,3,3,3)
    const float* __restrict__ b3,     // (3)
    const float* __restrict__ bias,   // (1)
    const h2* __restrict__ table,     // pair table or nullptr
    float* __restrict__ out)          // (N,3,H,W)
{
    __shared__ __align__(16) float simg[3 * IMROWS * 4 * IMJW]; // 19584 B
    __shared__ __align__(16) h2 sgrid[BY * XS * CELLE];         // 12672 B

    const int n  = blockIdx.z;
    const int wb = blockIdx.x * TILE_W;
    const int hb = blockIdx.y * BY;

    const float scale = 15.0f / 1023.0f;
    const int xlo = (int)(wb * scale);

    const int tid = threadIdx.y * BX + threadIdx.x;
    const size_t plane = (size_t)H * W;
    const float* fn = full + (size_t)n * 3 * plane;

    // ---- issue table loads FIRST (oldest in vmcnt queue) ----
    float4 tA[4], tB[4];
    const bool ttail = (tid < SGN - 768);   // 24 threads do a 4th element
    if (table) {
        const float4* tsrc = (const float4*)(table + (size_t)n * 256 * CELLE);
        #pragma unroll
        for (int it = 0; it < 3; ++it) {
            int e  = tid + 256 * it;
            int r  = e / (XS * CF4);
            int t2 = e - r * (XS * CF4);
            int lx = t2 / CF4, q = t2 - lx * CF4;
            int y0 = min((int)((float)(hb + r) * scale), GH - 2);
            int xi = min(xlo + lx, GW - 1);
            tA[it] = tsrc[(y0 * GW + xi) * CF4 + q];
            tB[it] = tsrc[((y0 + 1) * GW + xi) * CF4 + q];
        }
        if (ttail) {
            int e  = 768 + tid;
            int r  = e / (XS * CF4);
            int t2 = e - r * (XS * CF4);
            int lx = t2 / CF4, q = t2 - lx * CF4;
            int y0 = min((int)((float)(hb + r) * scale), GH - 2);
            int xi = min(xlo + lx, GW - 1);
            tA[3] = tsrc[(y0 * GW + xi) * CF4 + q];
            tB[3] = tsrc[((y0 + 1) * GW + xi) * CF4 + q];
        }
    }

    // ---- stage fullres tile: batch ALL loads into regs, THEN write LDS ----
    float4 vv[NIT];
    int    loff[NIT];
    #pragma unroll
    for (int it = 0; it < NIT; ++it) {
        int e = tid + 256 * it;
        loff[it] = -1;
        if (e < CHUNKS) {
            int ch = e / (IMROWS * NCHUNK);
            int t  = e - ch * (IMROWS * NCHUNK);
            int r  = t / NCHUNK, m = t - r * NCHUNK;
            int yy = hb + r - 1;
            int gx = wb - 4 + 4 * m;
            float4 v = (float4){0.0f, 0.0f, 0.0f, 0.0f};
            if ((unsigned)yy < (unsigned)H && (unsigned)gx < (unsigned)W)
                v = *(const float4*)(fn + (size_t)ch * plane + (size_t)yy * W + gx);
            vv[it]   = v;
            loff[it] = ((ch * IMROWS + r) * 4) * IMJW + m;
        }
    }
    #pragma unroll
    for (int it = 0; it < NIT; ++it) {
        if (loff[it] >= 0) {
            float* wp = &simg[loff[it]];
            wp[0 * IMJW] = vv[it].x;
            wp[1 * IMJW] = vv[it].y;
            wp[2 * IMJW] = vv[it].z;
            wp[3 * IMJW] = vv[it].w;
        }
    }
    __syncthreads();   // image slab ready

    // ---- sgrid: y-lerp from registers, write LDS (conv below overlaps) ----
    if (table) {
        float4* sdst = (float4*)sgrid;
        #pragma unroll
        for (int it = 0; it < 4; ++it) {
            if (it == 3 && !ttail) break;
            int e = (it == 3) ? (768 + tid) : (tid + 256 * it);
            int r = e / (XS * CF4);
            float fy = (float)(hb + r) * scale;
            float ty = fy - (float)min((int)fy, GH - 2);
            _Float16 t1 = (_Float16)ty, t0 = (_Float16)(1.0f - ty);
            h2 w0v = (h2){t0, t0}, w1v = (h2){t1, t1};
            float4 A = tA[it], B = tB[it], R;
            R.x = bcf(bch2(A.x) * w0v + bch2(B.x) * w1v);
            R.y = bcf(bch2(A.y) * w0v + bch2(B.y) * w1v);
            R.z = bcf(bch2(A.z) * w0v + bch2(B.z) * w1v);
            R.w = bcf(bch2(A.w) * w0v + bch2(B.w) * w1v);
            sdst[e] = R;
        }
    } else {
        const float* gnn = grid + (size_t)n * GC * GD * GH * GW;
        for (int e = tid; e < BY * XS * CELLE; e += BX * BY) {
            int r  = e / (XS * CELLE);
            int t  = e - r * (XS * CELLE);
            int lx = t / CELLE, u = t - lx * CELLE;
            int z0 = u / GC, c = u - z0 * GC;
            float fy = (float)(hb + r) * scale;
            int y0 = min((int)fy, GH - 2);
            float ty = fy - (float)y0;
            int xi = min(xlo + lx, GW - 1);
            const float* gp = gnn + ((c * GD + z0) * GH + y0) * GW + xi;
            float a0 = gp[0],  a1 = gp[256];
            float b0 = gp[16], b1 = gp[272];
            sgrid[e] = pkrtz(fmaf(b0 - a0, ty, a0), fmaf(b1 - a1, ty, a1));
        }
    }

    const int h  = hb + threadIdx.y;
    const int w0 = wb + threadIdx.x * PX;

    // ---- weights to registers ----
    float w1c[3][3];
    #pragma unroll
    for (int o = 0; o < 3; ++o)
        #pragma unroll
        for (int i = 0; i < 3; ++i)
            w1c[o][i] = w1[o * 3 + i];
    const float biasv = bias[0];

    // ---- 3x3 conv over 3 ch for 4 pixels; rows via conflict-free lane-major
    //      LDS reads, zero unpack (runs between barriers) ----
    v2f a3p[3][2];
    #pragma unroll
    for (int o = 0; o < 3; ++o) {
        float b = b3[o];
        a3p[o][0] = (v2f){b, b};
        a3p[o][1] = (v2f){b, b};
    }
    float rgb[3][PX];
    const int L = threadIdx.x;

    #pragma unroll
    for (int i = 0; i < 3; ++i) {
        #pragma unroll
        for (int dy = 0; dy < 3; ++dy) {
            const float* jp = &simg[((i * IMROWS + threadIdx.y + dy) * 4) * IMJW];
            float row[8];   // row[k] = pixel x = w0-1+k
            row[0] = jp[3 * IMJW + L];       // c=4L-1
            row[1] = jp[L + 1];              // c=4L
            row[2] = jp[1 * IMJW + L + 1];
            row[3] = jp[2 * IMJW + L + 1];
            row[4] = jp[3 * IMJW + L + 1];
            row[5] = jp[L + 2];              // c=4L+4
            row[6] = jp[1 * IMJW + L + 2];
            row[7] = jp[2 * IMJW + L + 2];
            if (dy == 1) {
                #pragma unroll
                for (int j = 0; j < PX; ++j) rgb[i][j] = row[1 + j];
            }
            #pragma unroll
            for (int o = 0; o < 3; ++o) {
                const float* kp = w3 + ((o * 3 + i) * 3 + dy) * 3;
                #pragma unroll
                for (int t = 0; t < 3; ++t) {
                    const float kt = kp[t];
                    v2f kv = (v2f){kt, kt};
                    a3p[o][0] = __builtin_elementwise_fma(
                        kv, (v2f){row[t], row[t + 1]}, a3p[o][0]);
                    a3p[o][1] = __builtin_elementwise_fma(
                        kv, (v2f){row[t + 2], row[t + 3]}, a3p[o][1]);
                }
            }
        }
    }
    __syncthreads();   // sgrid ready

    // ---- guide for all 4 px ----
    float gq[PX];
    #pragma unroll
    for (int j = 0; j < PX; ++j) {
        float gacc = 0.0f;
        #pragma unroll
        for (int o = 0; o < 3; ++o) {
            float x1 = fmaf(w1c[o][0], rgb[0][j],
                       fmaf(w1c[o][1], rgb[1][j], w1c[o][2] * rgb[2][j]));
            x1 = (x1 > 0.0f) ? x1 : LEAK * x1;
            float x3 = a3p[o][j >> 1][j & 1];
            x3 = (x3 > 0.0f) ? x3 : LEAK * x3;
            gacc += x1 + x3;
        }
        float g = fmaf(gacc, (1.0f / 3.0f), biasv);
        gq[j] = fminf(fmaxf(g, 0.0f), 1.0f);
    }

    const int srow = threadIdx.y * XS;       // this thread-row's cell base
    const float4* sg4 = (const float4*)sgrid;

    float4 ov0, ov1, ov2;
    float* ov0p = &ov0.x; float* ov1p = &ov1.x; float* ov2p = &ov2.x;

    // ---- slice+apply, pixel-PAIR batched (12 b128 in flight per pair);
    //      no launch-bounds cap -> VGPR floats, no spill (r11 lesson) ----
    #pragma unroll
    for (int jp2 = 0; jp2 < 2; ++jp2) {
        const int ja = 2 * jp2, jb = ja + 1;

        // coords px a
        float fxa = (float)(w0 + ja) * scale;
        int   x0a = min((int)fxa, GW - 2);
        float txa = fxa - (float)x0a;
        float fza = gq[ja] * 11.0f;
        int   z0a = min((int)fza, GD - 2);
        float tza = fza - (float)z0a;
        h2 hza = pkrtz(1.0f - tza, tza);
        _Float16 ax0 = (_Float16)(1.0f - txa), ax1 = (_Float16)txa;
        h2 wAa = hza * (h2){ax0, ax0};
        h2 wBa = hza * (h2){ax1, ax1};
        const float4* pAa = sg4 + (srow + x0a - xlo) * CF4 + z0a * 3;
        const float4* pBa = pAa + CF4;

        // coords px b
        float fxb = (float)(w0 + jb) * scale;
        int   x0b = min((int)fxb, GW - 2);
        float txb = fxb - (float)x0b;
        float fzb = gq[jb] * 11.0f;
        int   z0b = min((int)fzb, GD - 2);
        float tzb = fzb - (float)z0b;
        h2 hzb = pkrtz(1.0f - tzb, tzb);
        _Float16 bx0 = (_Float16)(1.0f - txb), bx1 = (_Float16)txb;
        h2 wAb = hzb * (h2){bx0, bx0};
        h2 wBb = hzb * (h2){bx1, bx1};
        const float4* pAb = sg4 + (srow + x0b - xlo) * CF4 + z0b * 3;
        const float4* pBb = pAb + CF4;

        // issue all 12 LDS reads for the pair
        float4 Aa0 = pAa[0], Aa1 = pAa[1], Aa2 = pAa[2];
        float4 Ba0 = pBa[0], Ba1 = pBa[1], Ba2 = pBa[2];
        float4 Ab0 = pAb[0], Ab1 = pAb[1], Ab2 = pAb[2];
        float4 Bb0 = pBb[0], Bb1 = pBb[1], Bb2 = pBb[2];

        {
            const float r = rgb[0][ja], gg = rgb[1][ja], b = rgb[2][ja];
            float c0, c1, c2, c3;
            c0 = fdot2f(wAa, bch2(Aa0.x), fdot2f(wBa, bch2(Ba0.x), 0.0f));
            c1 = fdot2f(wAa, bch2(Aa0.y), fdot2f(wBa, bch2(Ba0.y), 0.0f));
            c2 = fdot2f(wAa, bch2(Aa0.z), fdot2f(wBa, bch2(Ba0.z), 0.0f));
            c3 = fdot2f(wAa, bch2(Aa0.w), fdot2f(wBa, bch2(Ba0.w), 0.0f));
            ov0p[ja] = fmaf(c0, r, fmaf(c1, gg, fmaf(c2, b, c3)));
            c0 = fdot2f(wAa, bch2(Aa1.x), fdot2f(wBa, bch2(Ba1.x), 0.0f));
            c1 = fdot2f(wAa, bch2(Aa1.y), fdot2f(wBa, bch2(Ba1.y), 0.0f));
            c2 = fdot2f(wAa, bch2(Aa1.z), fdot2f(wBa, bch2(Ba1.z), 0.0f));
            c3 = fdot2f(wAa, bch2(Aa1.w), fdot2f(wBa, bch2(Ba1.w), 0.0f));
            ov1p[ja] = fmaf(c0, r, fmaf(c1, gg, fmaf(c2, b, c3)));
            c0 = fdot2f(wAa, bch2(Aa2.x), fdot2f(wBa, bch2(Ba2.x), 0.0f));
            c1 = fdot2f(wAa, bch2(Aa2.y), fdot2f(wBa, bch2(Ba2.y), 0.0f));
            c2 = fdot2f(wAa, bch2(Aa2.z), fdot2f(wBa, bch2(Ba2.z), 0.0f));
            c3 = fdot2f(wAa, bch2(Aa2.w), fdot2f(wBa, bch2(Ba2.w), 0.0f));
            ov2p[ja] = fmaf(c0, r, fmaf(c1, gg, fmaf(c2, b, c3)));
        }
        {
            const float r = rgb[0][jb], gg = rgb[1][jb], b = rgb[2][jb];
            float c0, c1, c2, c3;
            c0 = fdot2f(wAb, bch2(Ab0.x), fdot2f(wBb, bch2(Bb0.x), 0.0f));
            c1 = fdot2f(wAb, bch2(Ab0.y), fdot2f(wBb, bch2(Bb0.y), 0.0f));
            c2 = fdot2f(wAb, bch2(Ab0.z), fdot2f(wBb, bch2(Bb0.z), 0.0f));
            c3 = fdot2f(wAb, bch2(Ab0.w), fdot2f(wBb, bch2(Bb0.w), 0.0f));
            ov0p[jb] = fmaf(c0, r, fmaf(c1, gg, fmaf(c2, b, c3)));
            c0 = fdot2f(wAb, bch2(Ab1.x), fdot2f(wBb, bch2(Bb1.x), 0.0f));
            c1 = fdot2f(wAb, bch2(Ab1.y), fdot2f(wBb, bch2(Bb1.y), 0.0f));
            c2 = fdot2f(wAb, bch2(Ab1.z), fdot2f(wBb, bch2(Bb1.z), 0.0f));
            c3 = fdot2f(wAb, bch2(Ab1.w), fdot2f(wBb, bch2(Bb1.w), 0.0f));
            ov1p[jb] = fmaf(c0, r, fmaf(c1, gg, fmaf(c2, b, c3)));
            c0 = fdot2f(wAb, bch2(Ab2.x), fdot2f(wBb, bch2(Bb2.x), 0.0f));
            c1 = fdot2f(wAb, bch2(Ab2.y), fdot2f(wBb, bch2(Bb2.y), 0.0f));
            c2 = fdot2f(wAb, bch2(Ab2.z), fdot2f(wBb, bch2(Bb2.z), 0.0f));
            c3 = fdot2f(wAb, bch2(Ab2.w), fdot2f(wBb, bch2(Bb2.w), 0.0f));
            ov2p[jb] = fmaf(c0, r, fmaf(c1, gg, fmaf(c2, b, c3)));
        }
    }

    // ---- coalesced float4 stores ----
    float* ob = out + (size_t)n * 3 * plane + (size_t)h * W + w0;
    *(float4*)(ob)             = ov0;
    *(float4*)(ob + plane)     = ov1;
    *(float4*)(ob + 2 * plane) = ov2;
}

extern "C" void kernel_launch(void* const* d_in, const int* in_sizes, int n_in,
                              void* d_out, int out_size, void* d_ws, size_t ws_size,
                              hipStream_t stream) {
    const float* grid_p = (const float*)d_in[0];
    const float* full_p = (const float*)d_in[1];
    const float* w1_p   = (const float*)d_in[2];
    const float* w3_p   = (const float*)d_in[3];
    const float* b3_p   = (const float*)d_in[4];
    const float* bias_p = (const float*)d_in[5];
    float* out_p = (float*)d_out;

    const size_t tbytes = (size_t)NIMG * 256 * CELLE * sizeof(h2);  // 540,672 B
    h2* table = (d_ws && ws_size >= tbytes) ? (h2*)d_ws : nullptr;

    if (table) {
        hipLaunchKernelGGL(pairgen, dim3(NIMG * NZ), dim3(256), 0, stream,
                           grid_p, table);
    }

    dim3 block(BX, BY, 1);
    dim3 grid_dim(W / TILE_W, H / BY, NIMG);
    hipLaunchKernelGGL(hdrnet_fused, grid_dim, block, 0, stream,
                       grid_p, full_p, w1_p, w3_p, b3_p, bias_p, table, out_p);
}